// Round 4
// baseline (470.534 us; speedup 1.0000x reference)
//
#include <hip/hip_runtime.h>
#include <hip/hip_bf16.h>

#define SEGS   16384
#define DCH    128
#define CHUNK  32
#define SEGPB  8          // consecutive segments per block
#define HPITCH 136        // bf16 plane pitch (shorts) = 272B
#define FPITCH 132        // fp32 plane pitch (floats) = 528B
#define LOG2E  1.4426950408889634f

using f32x4  = __attribute__((ext_vector_type(4))) float;
using bf16x8 = __attribute__((ext_vector_type(8))) short;
using u32x2  = __attribute__((ext_vector_type(2))) unsigned int;
using u32x4  = __attribute__((ext_vector_type(4))) unsigned int;

__device__ __forceinline__ float u2f(unsigned int u) { return __uint_as_float(u); }
__device__ __forceinline__ unsigned int f2u(float f) { return __float_as_uint(f); }

// ---------------------------------------------------------------------------
// Setup: (a) W' = W * log2e -> fragment-ready bf16 hi/lo B-operand layout
//        (b) per-segment row starts via binary search on sorted index
// ---------------------------------------------------------------------------
__global__ void setup_kernel(const float* __restrict__ W,
                             const int* __restrict__ index, int N,
                             unsigned short* __restrict__ WfH,
                             unsigned short* __restrict__ WfL,
                             int* __restrict__ seg_start) {
  int i = blockIdx.x * blockDim.x + threadIdx.x;
  if (i < DCH * DCH) {
    int n = i >> 7, k = i & 127;           // W[n][k]
    float w = W[i] * LOG2E;                // fold log2e -> raw exp2 in softmax
    unsigned int u = f2u(w);
    unsigned int hu = u & 0xFFFF0000u;     // truncated bf16 hi
    float lo = w - u2f(hu);                // residual -> bf16 lo
    int kt    = k >> 5;
    int ntile = n >> 4;
    int lane  = (n & 15) + 16 * ((k >> 3) & 3);
    int j     = k & 7;
    int dst = ((kt * 8 + ntile) * 64 + lane) * 8 + j;
    WfH[dst] = (unsigned short)(u >> 16);
    WfL[dst] = (unsigned short)(f2u(lo) >> 16);
  } else if (i < DCH * DCH + SEGS + 1) {
    int s = i - DCH * DCH;                 // lower_bound(index, s)
    int lo = 0, hi = N;
    while (lo < hi) {
      int mid = (lo + hi) >> 1;
      if (index[mid] < s) lo = mid + 1; else hi = mid;
    }
    seg_start[s] = lo;
  }
}

// ---------------------------------------------------------------------------
// Main: block b owns segments [8b, 8b+8). 4 waves; wave w owns channels
// [32w, 32w+32). One-chunk-deep software pipeline: chunk c+1's global loads
// are issued during chunk c's phases, and barriers are raw s_barrier with
// lgkmcnt-only waits so the prefetch stays in flight across barriers.
// ---------------------------------------------------------------------------
__global__ __launch_bounds__(256, 4) void pool_kernel(
    const float* __restrict__ x, const float* __restrict__ bias,
    const int* __restrict__ seg_start,
    const u32x4* __restrict__ WfH, const u32x4* __restrict__ WfL,
    float* __restrict__ out) {
  __shared__ unsigned short xh[CHUNK * HPITCH];
  __shared__ unsigned short xl[CHUNK * HPITCH];
  __shared__ float          xf[CHUNK * FPITCH];

  const int t    = threadIdx.x;
  const int wv   = t >> 6;
  const int lane = t & 63;
  const int cl   = lane & 15;              // A-row sel / C col within 16-tile
  const int g    = lane >> 4;              // lane group (k-slice / row group)
  const int lrow = t >> 5;                 // staging: rows 0..7 (+8 per p)
  const int lcol = (t & 31) << 2;          // staging: f32x4 col

  // Register-resident B fragments (this wave's 32 channels), hi & lo — once.
  u32x4 bh[4][2], bl[4][2];
#pragma unroll
  for (int kt = 0; kt < 4; ++kt)
#pragma unroll
    for (int nt = 0; nt < 2; ++nt) {
      int off = (kt * 8 + (wv * 2 + nt)) * 64 + lane;   // 16B units
      bh[kt][nt] = WfH[off];
      bl[kt][nt] = WfL[off];
    }

  const float bc0 = bias[wv * 32 + cl]      * LOG2E;
  const float bc1 = bias[wv * 32 + 16 + cl] * LOG2E;

  const int s0   = blockIdx.x * SEGPB;
  const int sEnd = s0 + SEGPB;

  // Empty segments (rare): write zeros outside the pipeline, keep CF uniform.
  for (int es = s0; es < sEnd; ++es) {
    if (seg_start[es + 1] == seg_start[es] && lane < 16) {
      out[(size_t)es * DCH + wv * 32 + cl]      = 0.f;
      out[(size_t)es * DCH + wv * 32 + 16 + cl] = 0.f;
    }
  }

  int s = s0;
  while (s < sEnd && seg_start[s + 1] == seg_start[s]) ++s;
  if (s >= sEnd) return;                   // whole block empty (uniform exit)

  int c0  = 0;
  int len = seg_start[s + 1] - seg_start[s];
  int cnt = (len < CHUNK) ? len : CHUNK;

  // Prefetch first chunk into registers (rows >= cnt zero-filled).
  f32x4 pv[4];
  {
    const int base = seg_start[s];
#pragma unroll
    for (int p = 0; p < 4; ++p) {
      int lr = lrow + p * 8;
      f32x4 v = {0.f, 0.f, 0.f, 0.f};
      if (lr < cnt) v = *(const f32x4*)(x + (size_t)(base + lr) * DCH + lcol);
      pv[p] = v;
    }
  }

  float den[2] = {0.f, 0.f};
  float num[2] = {0.f, 0.f};

  while (true) {
    // ---- next-chunk coordinates (wave-uniform scalar work) ----
    int ns = s, nc0 = c0 + CHUNK;
    if (nc0 >= len) {
      nc0 = 0; ns = s + 1;
      while (ns < sEnd && seg_start[ns + 1] == seg_start[ns]) ++ns;
    }
    const bool have_next = (ns < sEnd);
    int nlen = 0, ncnt = 0, nbase = 0;
    if (have_next) {
      nbase = seg_start[ns] + nc0;
      nlen  = seg_start[ns + 1] - seg_start[ns];
      ncnt  = nlen - nc0; if (ncnt > CHUNK) ncnt = CHUNK;
    }

    // ---- barrier A: all waves done READING LDS of previous chunk ----
    asm volatile("s_waitcnt lgkmcnt(0)" ::: "memory");
    __builtin_amdgcn_sched_barrier(0);
    __builtin_amdgcn_s_barrier();          // raw: does NOT drain vmcnt
    __builtin_amdgcn_sched_barrier(0);

    // ---- convert prefetched regs -> LDS planes (vmcnt wait lands here) ----
#pragma unroll
    for (int p = 0; p < 4; ++p) {
      int lr = lrow + p * 8;
      f32x4 v = pv[p];
      unsigned int u0 = f2u(v[0]), u1 = f2u(v[1]), u2 = f2u(v[2]), u3 = f2u(v[3]);
      unsigned int h0 = u0 & 0xFFFF0000u, h1 = u1 & 0xFFFF0000u;
      unsigned int h2 = u2 & 0xFFFF0000u, h3 = u3 & 0xFFFF0000u;
      float l0f = v[0] - u2f(h0), l1f = v[1] - u2f(h1);
      float l2f = v[2] - u2f(h2), l3f = v[3] - u2f(h3);
      u32x2 H = { h1 | (u0 >> 16), h3 | (u2 >> 16) };
      u32x2 L = { (f2u(l1f) & 0xFFFF0000u) | (f2u(l0f) >> 16),
                  (f2u(l3f) & 0xFFFF0000u) | (f2u(l2f) >> 16) };
      *(u32x2*)&xh[lr * HPITCH + lcol] = H;
      *(u32x2*)&xl[lr * HPITCH + lcol] = L;
      *(f32x4*)&xf[lr * FPITCH + lcol] = v;
    }

    // ---- issue next chunk's global loads (in flight through MFMA phase) ----
    if (have_next) {
#pragma unroll
      for (int p = 0; p < 4; ++p) {
        int lr = lrow + p * 8;
        f32x4 v = {0.f, 0.f, 0.f, 0.f};
        if (lr < ncnt) v = *(const f32x4*)(x + (size_t)(nbase + lr) * DCH + lcol);
        pv[p] = v;
      }
    }

    // ---- barrier B: LDS planes ready (again: no vmcnt drain) ----
    asm volatile("s_waitcnt lgkmcnt(0)" ::: "memory");
    __builtin_amdgcn_sched_barrier(0);
    __builtin_amdgcn_s_barrier();
    __builtin_amdgcn_sched_barrier(0);

    // ---- att' = (x @ W'^T + b') for this chunk (this wave's 32 cols) ----
    f32x4 Cf[2][2];
#pragma unroll
    for (int mt = 0; mt < 2; ++mt) {
      Cf[mt][0] = (f32x4){bc0, bc0, bc0, bc0};
      Cf[mt][1] = (f32x4){bc1, bc1, bc1, bc1};
    }

#pragma unroll
    for (int kt = 0; kt < 4; ++kt) {
      u32x4 ah[2], al[2];
#pragma unroll
      for (int mt = 0; mt < 2; ++mt) {
        const unsigned short* p0 = &xh[(mt * 16 + cl) * HPITCH + kt * 32 + g * 8];
        const unsigned short* p1 = &xl[(mt * 16 + cl) * HPITCH + kt * 32 + g * 8];
        ah[mt] = *(const u32x4*)p0;
        al[mt] = *(const u32x4*)p1;
      }
#pragma unroll
      for (int sp = 0; sp < 3; ++sp)       // hh, hl, lh
#pragma unroll
        for (int mt = 0; mt < 2; ++mt)
#pragma unroll
          for (int nt = 0; nt < 2; ++nt) {
            bf16x8 A = __builtin_bit_cast(bf16x8, (sp == 2) ? al[mt] : ah[mt]);
            bf16x8 B = __builtin_bit_cast(bf16x8, (sp == 1) ? bl[kt][nt] : bh[kt][nt]);
            Cf[mt][nt] = __builtin_amdgcn_mfma_f32_16x16x32_bf16(A, B, Cf[mt][nt], 0, 0, 0);
          }
    }

    // ---- e = exp2(att'); accumulate den/num (no max: |att'| bounded) ----
    // C layout: col = lane&15, row(in 16-tile) = g*4 + reg   [m89/m91]
#pragma unroll
    for (int nt = 0; nt < 2; ++nt) {
      const int cidx = wv * 32 + nt * 16 + cl;
#pragma unroll
      for (int mt = 0; mt < 2; ++mt)
#pragma unroll
        for (int r = 0; r < 4; ++r) {
          int row = mt * 16 + g * 4 + r;
          if (row < cnt) {
            float p = __builtin_amdgcn_exp2f(Cf[mt][nt][r]);
            den[nt] += p;
            num[nt] += p * xf[row * FPITCH + cidx];
          }
        }
    }

    // ---- segment bookkeeping ----
    if (c0 + CHUNK >= len) {               // segment s complete -> store
#pragma unroll
      for (int nt = 0; nt < 2; ++nt) {
        float l = den[nt], a = num[nt];
        l += __shfl_xor(l, 16); l += __shfl_xor(l, 32);
        a += __shfl_xor(a, 16); a += __shfl_xor(a, 32);
        if (lane < 16)
          out[(size_t)s * DCH + wv * 32 + nt * 16 + cl] = a / (l + 1e-16f);
        den[nt] = 0.f; num[nt] = 0.f;
      }
      if (!have_next) break;
      s = ns; len = nlen; c0 = 0;
    } else {
      c0 = nc0;
    }
    cnt = ncnt;
  }
}

extern "C" void kernel_launch(void* const* d_in, const int* in_sizes, int n_in,
                              void* d_out, int out_size, void* d_ws, size_t ws_size,
                              hipStream_t stream) {
  const float* x    = (const float*)d_in[0];
  const float* W    = (const float*)d_in[1];
  const float* bias = (const float*)d_in[2];
  const int*   idx  = (const int*)d_in[3];
  const int N = in_sizes[0] / DCH;

  unsigned short* WfH = (unsigned short*)d_ws;            // 32 KB
  unsigned short* WfL = WfH + DCH * DCH;                  // 32 KB
  int* seg = (int*)(WfL + DCH * DCH);                     // (SEGS+1)*4 B

  int setup_threads = DCH * DCH + SEGS + 1;
  setup_kernel<<<(setup_threads + 255) / 256, 256, 0, stream>>>(W, idx, N, WfH, WfL, seg);
  pool_kernel<<<SEGS / SEGPB, 256, 0, stream>>>(x, bias, seg,
                                                (const u32x4*)WfH, (const u32x4*)WfL,
                                                (float*)d_out);
}

// Round 5
// 237.231 us; speedup vs baseline: 1.9834x; 1.9834x over previous
//
#include <hip/hip_runtime.h>
#include <hip/hip_bf16.h>

#define SEGS   16384
#define DCH    128
#define CHUNK  32
#define SEGPB  4          // consecutive segments per block
#define HPITCH 136        // bf16 plane pitch (shorts) = 272B
#define LOG2E  1.4426950408889634f

using f32x4  = __attribute__((ext_vector_type(4))) float;
using bf16x8 = __attribute__((ext_vector_type(8))) short;
using u32x2  = __attribute__((ext_vector_type(2))) unsigned int;
using u32x4  = __attribute__((ext_vector_type(4))) unsigned int;

__device__ __forceinline__ float u2f(unsigned int u) { return __uint_as_float(u); }
__device__ __forceinline__ unsigned int f2u(float f) { return __float_as_uint(f); }

// ---------------------------------------------------------------------------
// Setup: (a) W' = W * log2e -> fragment-ready bf16 hi/lo B-operand layout
//        (b) per-segment row starts via binary search on sorted index
// ---------------------------------------------------------------------------
__global__ void setup_kernel(const float* __restrict__ W,
                             const int* __restrict__ index, int N,
                             unsigned short* __restrict__ WfH,
                             unsigned short* __restrict__ WfL,
                             int* __restrict__ seg_start) {
  int i = blockIdx.x * blockDim.x + threadIdx.x;
  if (i < DCH * DCH) {
    int n = i >> 7, k = i & 127;           // W[n][k]
    float w = W[i] * LOG2E;                // fold log2e -> raw exp2 in softmax
    unsigned int u = f2u(w);
    unsigned int hu = u & 0xFFFF0000u;     // truncated bf16 hi
    float lo = w - u2f(hu);                // residual -> bf16 lo
    int kt    = k >> 5;
    int ntile = n >> 4;
    int lane  = (n & 15) + 16 * ((k >> 3) & 3);
    int j     = k & 7;
    int dst = ((kt * 8 + ntile) * 64 + lane) * 8 + j;
    WfH[dst] = (unsigned short)(u >> 16);
    WfL[dst] = (unsigned short)(f2u(lo) >> 16);
  } else if (i < DCH * DCH + SEGS + 1) {
    int s = i - DCH * DCH;                 // lower_bound(index, s)
    int lo = 0, hi = N;
    while (lo < hi) {
      int mid = (lo + hi) >> 1;
      if (index[mid] < s) lo = mid + 1; else hi = mid;
    }
    seg_start[s] = lo;
  }
}

// ---------------------------------------------------------------------------
// Main: block b owns segments [4b, 4b+4). 4 waves; wave w owns channels
// [32w, 32w+32). 2-buffer LDS pipeline, one raw s_barrier per chunk;
// next chunk's global loads stay in flight across the barrier (no vmcnt
// drain). x is held in LDS only as bf16 hi/lo planes; the e*x accumulation
// reconstructs x = hi + lo (error ~2^-17, negligible).
// ---------------------------------------------------------------------------
__global__ __launch_bounds__(256) void pool_kernel(
    const float* __restrict__ x, const float* __restrict__ bias,
    const int* __restrict__ seg_start,
    const u32x4* __restrict__ WfH, const u32x4* __restrict__ WfL,
    float* __restrict__ out) {
  __shared__ unsigned short xh[2][CHUNK * HPITCH];
  __shared__ unsigned short xl[2][CHUNK * HPITCH];

  const int t    = threadIdx.x;
  const int wv   = t >> 6;
  const int lane = t & 63;
  const int cl   = lane & 15;              // A-row sel / C col within 16-tile
  const int g    = lane >> 4;              // lane group (k-slice / row group)
  const int lrow = t >> 5;                 // staging: rows 0..7 (+8 per p)
  const int lcol = (t & 31) << 2;          // staging: f32x4 col

  // Register-resident B fragments (this wave's 32 channels), hi & lo — once.
  u32x4 bh[4][2], bl[4][2];
#pragma unroll
  for (int kt = 0; kt < 4; ++kt)
#pragma unroll
    for (int nt = 0; nt < 2; ++nt) {
      int off = (kt * 8 + (wv * 2 + nt)) * 64 + lane;   // 16B units
      bh[kt][nt] = WfH[off];
      bl[kt][nt] = WfL[off];
    }

  const float bc0 = bias[wv * 32 + cl]      * LOG2E;
  const float bc1 = bias[wv * 32 + 16 + cl] * LOG2E;

  const int s0   = blockIdx.x * SEGPB;
  const int sEnd = s0 + SEGPB;

  // Empty segments (rare): write zeros outside the pipeline, keep CF uniform.
  for (int es = s0; es < sEnd; ++es) {
    if (seg_start[es + 1] == seg_start[es] && lane < 16) {
      out[(size_t)es * DCH + wv * 32 + cl]      = 0.f;
      out[(size_t)es * DCH + wv * 32 + 16 + cl] = 0.f;
    }
  }

  int s = s0;
  while (s < sEnd && seg_start[s + 1] == seg_start[s]) ++s;
  if (s >= sEnd) return;                   // whole block empty (uniform exit)

  int c0  = 0;
  int len = seg_start[s + 1] - seg_start[s];
  int cnt = (len < CHUNK) ? len : CHUNK;

  // Prefetch first chunk into registers (rows >= cnt zero-filled).
  f32x4 pv[4];
  {
    const int base = seg_start[s];
#pragma unroll
    for (int p = 0; p < 4; ++p) {
      int lr = lrow + p * 8;
      f32x4 v = {0.f, 0.f, 0.f, 0.f};
      if (lr < cnt) v = *(const f32x4*)(x + (size_t)(base + lr) * DCH + lcol);
      pv[p] = v;
    }
  }

  float den[2] = {0.f, 0.f};
  float num[2] = {0.f, 0.f};
  int buf = 0;

  while (true) {
    // ---- next-chunk coordinates (wave-uniform scalar work) ----
    int ns = s, nc0 = c0 + CHUNK;
    if (nc0 >= len) {
      nc0 = 0; ns = s + 1;
      while (ns < sEnd && seg_start[ns + 1] == seg_start[ns]) ++ns;
    }
    const bool have_next = (ns < sEnd);
    int nlen = 0, ncnt = 0, nbase = 0;
    if (have_next) {
      nbase = seg_start[ns] + nc0;
      nlen  = seg_start[ns + 1] - seg_start[ns];
      ncnt  = nlen - nc0; if (ncnt > CHUNK) ncnt = CHUNK;
    }

    // ---- convert prefetched regs -> LDS planes buf (vmcnt wait lands here) --
    unsigned short* XH = &xh[buf][0];
    unsigned short* XL = &xl[buf][0];
#pragma unroll
    for (int p = 0; p < 4; ++p) {
      int lr = lrow + p * 8;
      f32x4 v = pv[p];
      unsigned int u0 = f2u(v[0]), u1 = f2u(v[1]), u2 = f2u(v[2]), u3 = f2u(v[3]);
      unsigned int h0 = u0 & 0xFFFF0000u, h1 = u1 & 0xFFFF0000u;
      unsigned int h2 = u2 & 0xFFFF0000u, h3 = u3 & 0xFFFF0000u;
      float l0f = v[0] - u2f(h0), l1f = v[1] - u2f(h1);
      float l2f = v[2] - u2f(h2), l3f = v[3] - u2f(h3);
      u32x2 H = { h1 | (u0 >> 16), h3 | (u2 >> 16) };
      u32x2 L = { (f2u(l1f) & 0xFFFF0000u) | (f2u(l0f) >> 16),
                  (f2u(l3f) & 0xFFFF0000u) | (f2u(l2f) >> 16) };
      *(u32x2*)&XH[lr * HPITCH + lcol] = H;
      *(u32x2*)&XL[lr * HPITCH + lcol] = L;
    }

    // ---- issue next chunk's global loads (in flight through MFMA phase) ----
    if (have_next) {
#pragma unroll
      for (int p = 0; p < 4; ++p) {
        int lr = lrow + p * 8;
        f32x4 v = {0.f, 0.f, 0.f, 0.f};
        if (lr < ncnt) v = *(const f32x4*)(x + (size_t)(nbase + lr) * DCH + lcol);
        pv[p] = v;
      }
    }

    // ---- single barrier: planes of buf ready; prefetch NOT drained ----
    asm volatile("s_waitcnt lgkmcnt(0)" ::: "memory");
    __builtin_amdgcn_sched_barrier(0);
    __builtin_amdgcn_s_barrier();
    __builtin_amdgcn_sched_barrier(0);

    // ---- att' = (x @ W'^T + b') for this chunk (this wave's 32 cols) ----
    f32x4 Cf[2][2];
#pragma unroll
    for (int mt = 0; mt < 2; ++mt) {
      Cf[mt][0] = (f32x4){bc0, bc0, bc0, bc0};
      Cf[mt][1] = (f32x4){bc1, bc1, bc1, bc1};
    }

#pragma unroll
    for (int kt = 0; kt < 4; ++kt) {
      u32x4 ah[2], al[2];
#pragma unroll
      for (int mt = 0; mt < 2; ++mt) {
        const unsigned short* p0 = &XH[(mt * 16 + cl) * HPITCH + kt * 32 + g * 8];
        const unsigned short* p1 = &XL[(mt * 16 + cl) * HPITCH + kt * 32 + g * 8];
        ah[mt] = *(const u32x4*)p0;
        al[mt] = *(const u32x4*)p1;
      }
#pragma unroll
      for (int sp = 0; sp < 3; ++sp)       // hh, hl, lh
#pragma unroll
        for (int mt = 0; mt < 2; ++mt)
#pragma unroll
          for (int nt = 0; nt < 2; ++nt) {
            bf16x8 A = __builtin_bit_cast(bf16x8, (sp == 2) ? al[mt] : ah[mt]);
            bf16x8 B = __builtin_bit_cast(bf16x8, (sp == 1) ? bl[kt][nt] : bh[kt][nt]);
            Cf[mt][nt] = __builtin_amdgcn_mfma_f32_16x16x32_bf16(A, B, Cf[mt][nt], 0, 0, 0);
          }
    }

    // ---- e = exp2(att'); accumulate den/num (no max: |att'| bounded) ----
    // C layout: col = lane&15, row(in 16-tile) = g*4 + reg   [m89/m91]
#pragma unroll
    for (int nt = 0; nt < 2; ++nt) {
      const int cidx = wv * 32 + nt * 16 + cl;
#pragma unroll
      for (int mt = 0; mt < 2; ++mt)
#pragma unroll
        for (int r = 0; r < 4; ++r) {
          int row = mt * 16 + g * 4 + r;
          if (row < cnt) {
            float p = __builtin_amdgcn_exp2f(Cf[mt][nt][r]);
            unsigned int hv = XH[row * HPITCH + cidx];
            unsigned int lv = XL[row * HPITCH + cidx];
            float xv = u2f(hv << 16) + u2f(lv << 16);
            den[nt] += p;
            num[nt] += p * xv;
          }
        }
    }

    // ---- segment bookkeeping ----
    if (c0 + CHUNK >= len) {               // segment s complete -> store
#pragma unroll
      for (int nt = 0; nt < 2; ++nt) {
        float l = den[nt], a = num[nt];
        l += __shfl_xor(l, 16); l += __shfl_xor(l, 32);
        a += __shfl_xor(a, 16); a += __shfl_xor(a, 32);
        if (lane < 16)
          out[(size_t)s * DCH + wv * 32 + nt * 16 + cl] = a / (l + 1e-16f);
        den[nt] = 0.f; num[nt] = 0.f;
      }
      if (!have_next) break;
      s = ns; len = nlen; c0 = 0;
    } else {
      c0 = nc0;
    }
    cnt = ncnt;
    buf ^= 1;
  }
}

extern "C" void kernel_launch(void* const* d_in, const int* in_sizes, int n_in,
                              void* d_out, int out_size, void* d_ws, size_t ws_size,
                              hipStream_t stream) {
  const float* x    = (const float*)d_in[0];
  const float* W    = (const float*)d_in[1];
  const float* bias = (const float*)d_in[2];
  const int*   idx  = (const int*)d_in[3];
  const int N = in_sizes[0] / DCH;

  unsigned short* WfH = (unsigned short*)d_ws;            // 32 KB
  unsigned short* WfL = WfH + DCH * DCH;                  // 32 KB
  int* seg = (int*)(WfL + DCH * DCH);                     // (SEGS+1)*4 B

  int setup_threads = DCH * DCH + SEGS + 1;
  setup_kernel<<<(setup_threads + 255) / 256, 256, 0, stream>>>(W, idx, N, WfH, WfL, seg);
  pool_kernel<<<SEGS / SEGPB, 256, 0, stream>>>(x, bias, seg,
                                                (const u32x4*)WfH, (const u32x4*)WfL,
                                                (float*)d_out);
}